// Round 8
// baseline (149.527 us; speedup 1.0000x reference)
//
#include <hip/hip_runtime.h>
#include <hip/hip_bf16.h>
#include <stdint.h>

// Spiking ensemble update. S=16384. W=[S][S] f32 (1 GiB). lateral = spikes @ W:
// only spiking rows (~50%) read -> ~537 MB floor ~ 84 us at read ceiling.
// Outputs: flat f32 concat [spikes, activation, threshold, freq].
// History: R2 branchy 2.1 TB/s; R3 compact+4KB 3.7; R4 16KB+NT 5.4; R5 global
// partition NEUTRAL; R6 TPB=1024 REGRESSED (no backfill); R7 fused prep 105us
// (lateral ~87% of fill BW). R8: fixed-point int64 atomic accumulation --
// removes 32 MB partial round-trip + shrinks update kernel to a 128 KB read.
// Integer atomics are associative -> bitwise deterministic.

constexpr int S = 16384;
constexpr int TPB = 256;
constexpr int RPC = 64;                    // rows per chunk (one ballot)
constexpr int N_CHUNKS = S / RPC;          // 256
constexpr int COL_BLOCKS = 4;              // 4096 cols = 16 KB per row visit
constexpr int COLW = S / COL_BLOCKS;

constexpr double FP_SCALE = 17592186044416.0;   // 2^44

typedef float  f32x4 __attribute__((ext_vector_type(4)));
typedef double f64x4 __attribute__((ext_vector_type(4)));

// dtype code: 0=int32, 1=uint8/bool, 2=f32, 3=bf16
__device__ __forceinline__ bool spike_flag(const void* sp, int c, int r) {
  if (c == 0) return ((const int*)sp)[r] != 0;
  if (c == 1) return ((const unsigned char*)sp)[r] != 0;
  if (c == 2) return ((const float*)sp)[r] != 0.0f;
  return ((const unsigned short*)sp)[r] != 0;
}

// Classify spike storage dtype from first S bytes (L2/L3-hot after first use).
__device__ __forceinline__ int classify_local(const uint32_t* spw, int tid,
                                              int* sh3) {
  int l3a = 0, l3o = 0, lnz = 0;
  for (int w = tid; w < S / 4; w += TPB) {
    uint32_t v = spw[w];
#pragma unroll
    for (int b = 0; b < 4; ++b) {
      unsigned char byte = (v >> (8 * b)) & 0xFF;
      int i = w * 4 + b;
      if (byte == 0x3F) { l3a = 1; if ((i & 3) == 1) l3o = 1; }
      if (byte != 0 && (i & 3) != 0) lnz = 1;
    }
  }
  if (l3a) atomicOr(&sh3[0], 1);
  if (l3o) atomicOr(&sh3[1], 1);
  if (lnz) atomicOr(&sh3[2], 1);
  __syncthreads();
  return sh3[0] ? (sh3[1] ? 3 : 2) : (sh3[2] ? 1 : 0);
}

__device__ __forceinline__ void atomic_acc4(unsigned long long* acc, int col,
                                            f64x4 v) {
#pragma unroll
  for (int k = 0; k < 4; ++k) {
    long long d = (long long)llrint(v[k] * FP_SCALE);
    atomicAdd(acc + col + k, (unsigned long long)d);
  }
}

// ---- hot kernel: self-prep + stream 16 KB NT slices; int64 atomic finish ----
__global__ __launch_bounds__(TPB) void lateral_selfprep(
    const float* __restrict__ W, const void* __restrict__ sp,
    unsigned long long* __restrict__ acc) {
  __shared__ int sh3[3];
  __shared__ int ids[RPC];
  __shared__ int n_s;
  const int tid = threadIdx.x;
  if (tid < 3) sh3[tid] = 0;
  __syncthreads();
  const int c = classify_local((const uint32_t*)sp, tid, sh3);

  const int b = blockIdx.y;            // row chunk
  const int q = blockIdx.x;            // column quarter
  if (tid < 64) {
    int r = b * RPC + tid;
    bool f = spike_flag(sp, c, r);
    unsigned long long m = __ballot(f);
    int within = __popcll(m & ((1ULL << tid) - 1ULL));
    if (f) ids[within] = r;
    if (tid == 0) n_s = __popcll(m);
  }
  __syncthreads();
  const int n = n_s;

  const float* Wc = W + q * COLW + tid * 4;
  f64x4 a0 = 0.0, a1 = 0.0, a2 = 0.0, a3 = 0.0;
  int i = 0;
  for (; i + 2 <= n; i += 2) {
    const float* pa = Wc + (size_t)ids[i] * S;
    const float* pb = Wc + (size_t)ids[i + 1] * S;
    f32x4 wa0 = __builtin_nontemporal_load((const f32x4*)(pa));
    f32x4 wa1 = __builtin_nontemporal_load((const f32x4*)(pa + 1024));
    f32x4 wa2 = __builtin_nontemporal_load((const f32x4*)(pa + 2048));
    f32x4 wa3 = __builtin_nontemporal_load((const f32x4*)(pa + 3072));
    f32x4 wb0 = __builtin_nontemporal_load((const f32x4*)(pb));
    f32x4 wb1 = __builtin_nontemporal_load((const f32x4*)(pb + 1024));
    f32x4 wb2 = __builtin_nontemporal_load((const f32x4*)(pb + 2048));
    f32x4 wb3 = __builtin_nontemporal_load((const f32x4*)(pb + 3072));
    a0 += __builtin_convertvector(wa0, f64x4) + __builtin_convertvector(wb0, f64x4);
    a1 += __builtin_convertvector(wa1, f64x4) + __builtin_convertvector(wb1, f64x4);
    a2 += __builtin_convertvector(wa2, f64x4) + __builtin_convertvector(wb2, f64x4);
    a3 += __builtin_convertvector(wa3, f64x4) + __builtin_convertvector(wb3, f64x4);
  }
  if (i < n) {
    const float* pa = Wc + (size_t)ids[i] * S;
    a0 += __builtin_convertvector(__builtin_nontemporal_load((const f32x4*)(pa)), f64x4);
    a1 += __builtin_convertvector(__builtin_nontemporal_load((const f32x4*)(pa + 1024)), f64x4);
    a2 += __builtin_convertvector(__builtin_nontemporal_load((const f32x4*)(pa + 2048)), f64x4);
    a3 += __builtin_convertvector(__builtin_nontemporal_load((const f32x4*)(pa + 3072)), f64x4);
  }
  const int col0 = q * COLW + tid * 4;
  atomic_acc4(acc, col0, a0);
  atomic_acc4(acc, col0 + 1024, a1);
  atomic_acc4(acc, col0 + 2048, a2);
  atomic_acc4(acc, col0 + 3072, a3);
}

// ---- epilogue: read int64 accumulator (128 KB) + fused update ----
__device__ __forceinline__ void ensemble_epilogue(
    int j, float lateral,
    const float* __restrict__ x, const float* __restrict__ act,
    const float* __restrict__ thr, const float* __restrict__ freq,
    float* __restrict__ out) {
  float na = 0.9f * act[j] + x[j] + lateral;
  float t = thr[j];
  bool sp = na > t;
  float nf = 0.95f * freq[j] + 0.05f * (sp ? 1.0f : 0.0f);
  float nt = (nf > 0.2f) ? (t + 0.05f) : ((nf < 0.2f) ? (t / 1.05f) : t);
  if (sp) na = 0.0f;
  out[j]         = sp ? 1.0f : 0.0f;
  out[S + j]     = na;
  out[2 * S + j] = nt;
  out[3 * S + j] = nf;
}

__global__ __launch_bounds__(TPB) void ensemble_update(
    const unsigned long long* __restrict__ acc,
    const float* __restrict__ x, const float* __restrict__ act,
    const float* __restrict__ thr, const float* __restrict__ freq,
    float* __restrict__ out) {
  const int j = blockIdx.x * TPB + threadIdx.x;
  double lat = (double)(long long)acc[j] / FP_SCALE;
  ensemble_epilogue(j, (float)lat, x, act, thr, freq, out);
}

// ---- minimal fallback (ws too small; assumes int32 spikes) ----
__global__ __launch_bounds__(TPB) void fused_full_int(
    const float* __restrict__ W, const int* __restrict__ spikes,
    const float* __restrict__ x, const float* __restrict__ act,
    const float* __restrict__ thr, const float* __restrict__ freq,
    float* __restrict__ out) {
  const int j = blockIdx.x * TPB + threadIdx.x;
  double lat = 0.0;
  for (int i = 0; i < S; ++i)
    if (spikes[i] != 0) lat += (double)W[(size_t)i * S + j];
  ensemble_epilogue(j, (float)lat, x, act, thr, freq, out);
}

extern "C" void kernel_launch(void* const* d_in, const int* in_sizes, int n_in,
                              void* d_out, int out_size, void* d_ws, size_t ws_size,
                              hipStream_t stream) {
  const float* x    = (const float*)d_in[0];
  const float* act  = (const float*)d_in[1];
  const float* thr  = (const float*)d_in[2];
  const float* freq = (const float*)d_in[3];
  const float* W    = (const float*)d_in[4];
  const void*  sp   = d_in[5];
  float* out = (float*)d_out;

  const size_t need = (size_t)S * sizeof(unsigned long long);  // 128 KB

  if (ws_size >= need) {
    unsigned long long* acc = (unsigned long long*)d_ws;
    hipMemsetAsync(acc, 0, need, stream);   // zero accumulator (capture-safe)
    dim3 g1(COL_BLOCKS, N_CHUNKS);
    lateral_selfprep<<<g1, TPB, 0, stream>>>(W, sp, acc);
    ensemble_update<<<S / TPB, TPB, 0, stream>>>(acc, x, act, thr, freq, out);
  } else {
    fused_full_int<<<S / TPB, TPB, 0, stream>>>(W, (const int*)sp, x, act, thr, freq, out);
  }
}

// Round 9
// 97.312 us; speedup vs baseline: 1.5366x; 1.5366x over previous
//
#include <hip/hip_runtime.h>
#include <hip/hip_bf16.h>
#include <stdint.h>

// Spiking ensemble update. S=16384. W=[S][S] f32 (1 GiB). lateral = spikes @ W:
// only spiking rows (~50%) read -> ~537 MB floor ~ 84 us at read ceiling.
// Outputs: flat f32 concat [spikes, activation, threshold, freq].
// History: R2 branchy 2.1 TB/s; R3 compact+4KB 3.7; R4 16KB+NT 5.4; R5 global
// partition NEUTRAL; R6 TPB=1024 REGRESSED (no backfill); R7 fused-prep 105us
// (~87% of fill BW); R8 int64-atomic REGRESSED +45us (per-line RMW bursts).
// R9: R7 structure, 128-row chunks (partial 16->8 MB), 4-row unroll (16 MLP).

constexpr int S = 16384;
constexpr int TPB = 256;
constexpr int RPC = 128;                   // rows per chunk (2-wave ballot)
constexpr int N_CHUNKS = S / RPC;          // 128
constexpr int COL_BLOCKS = 4;              // 4096 cols = 16 KB per row visit
constexpr int COLW = S / COL_BLOCKS;

typedef float  f32x4 __attribute__((ext_vector_type(4)));
typedef double f64x4 __attribute__((ext_vector_type(4)));

// dtype code: 0=int32, 1=uint8/bool, 2=f32, 3=bf16
__device__ __forceinline__ bool spike_flag(const void* sp, int c, int r) {
  if (c == 0) return ((const int*)sp)[r] != 0;
  if (c == 1) return ((const unsigned char*)sp)[r] != 0;
  if (c == 2) return ((const float*)sp)[r] != 0.0f;
  return ((const unsigned short*)sp)[r] != 0;
}

// Classify spike storage dtype from first S bytes (L2/L3-hot after first use).
__device__ __forceinline__ int classify_local(const uint32_t* spw, int tid,
                                              int* sh3) {
  int l3a = 0, l3o = 0, lnz = 0;
  for (int w = tid; w < S / 4; w += TPB) {
    uint32_t v = spw[w];
#pragma unroll
    for (int b = 0; b < 4; ++b) {
      unsigned char byte = (v >> (8 * b)) & 0xFF;
      int i = w * 4 + b;
      if (byte == 0x3F) { l3a = 1; if ((i & 3) == 1) l3o = 1; }
      if (byte != 0 && (i & 3) != 0) lnz = 1;
    }
  }
  if (l3a) atomicOr(&sh3[0], 1);
  if (l3o) atomicOr(&sh3[1], 1);
  if (lnz) atomicOr(&sh3[2], 1);
  __syncthreads();
  return sh3[0] ? (sh3[1] ? 3 : 2) : (sh3[2] ? 1 : 0);
}

// ---- hot kernel: self-prep (classify + 2-wave ballot-compact 128 rows),
// then stream 16 KB NT slices of each spiking row. grid (4, 128). ----
__global__ __launch_bounds__(TPB) void lateral_selfprep(
    const float* __restrict__ W, const void* __restrict__ sp,
    float* __restrict__ partial) {
  __shared__ int sh3[3];
  __shared__ int ids[RPC];
  __shared__ int wcnt[2];
  const int tid = threadIdx.x;
  if (tid < 3) sh3[tid] = 0;
  __syncthreads();
  const int c = classify_local((const uint32_t*)sp, tid, sh3);

  const int b = blockIdx.y;            // row chunk
  const int q = blockIdx.x;            // column quarter
  const int lane = tid & 63, wv = tid >> 6;
  bool f = false;
  int within = 0;
  if (tid < RPC) {
    int r = b * RPC + tid;
    f = spike_flag(sp, c, r);
    unsigned long long m = __ballot(f);
    within = __popcll(m & ((1ULL << lane) - 1ULL));
    if (lane == 0) wcnt[wv] = __popcll(m);
  }
  __syncthreads();
  if (tid < RPC) {
    int off = (wv == 1) ? wcnt[0] : 0;
    if (f) ids[off + within] = b * RPC + tid;
  }
  __syncthreads();
  const int n = wcnt[0] + wcnt[1];

  const float* Wc = W + q * COLW + tid * 4;
  f64x4 a0 = 0.0, a1 = 0.0, a2 = 0.0, a3 = 0.0;
  int i = 0;
  for (; i + 4 <= n; i += 4) {
    f32x4 w0[4], w1[4], w2[4], w3[4];
#pragma unroll
    for (int u = 0; u < 4; ++u) {
      const float* p = Wc + (size_t)ids[i + u] * S;
      w0[u] = __builtin_nontemporal_load((const f32x4*)(p));
      w1[u] = __builtin_nontemporal_load((const f32x4*)(p + 1024));
      w2[u] = __builtin_nontemporal_load((const f32x4*)(p + 2048));
      w3[u] = __builtin_nontemporal_load((const f32x4*)(p + 3072));
    }
    a0 += __builtin_convertvector(w0[0], f64x4) + __builtin_convertvector(w0[1], f64x4)
        + __builtin_convertvector(w0[2], f64x4) + __builtin_convertvector(w0[3], f64x4);
    a1 += __builtin_convertvector(w1[0], f64x4) + __builtin_convertvector(w1[1], f64x4)
        + __builtin_convertvector(w1[2], f64x4) + __builtin_convertvector(w1[3], f64x4);
    a2 += __builtin_convertvector(w2[0], f64x4) + __builtin_convertvector(w2[1], f64x4)
        + __builtin_convertvector(w2[2], f64x4) + __builtin_convertvector(w2[3], f64x4);
    a3 += __builtin_convertvector(w3[0], f64x4) + __builtin_convertvector(w3[1], f64x4)
        + __builtin_convertvector(w3[2], f64x4) + __builtin_convertvector(w3[3], f64x4);
  }
  for (; i < n; ++i) {
    const float* p = Wc + (size_t)ids[i] * S;
    a0 += __builtin_convertvector(__builtin_nontemporal_load((const f32x4*)(p)), f64x4);
    a1 += __builtin_convertvector(__builtin_nontemporal_load((const f32x4*)(p + 1024)), f64x4);
    a2 += __builtin_convertvector(__builtin_nontemporal_load((const f32x4*)(p + 2048)), f64x4);
    a3 += __builtin_convertvector(__builtin_nontemporal_load((const f32x4*)(p + 3072)), f64x4);
  }
  float* dst = partial + (size_t)b * S + q * COLW + tid * 4;
  *(f32x4*)(dst)        = __builtin_convertvector(a0, f32x4);
  *(f32x4*)(dst + 1024) = __builtin_convertvector(a1, f32x4);
  *(f32x4*)(dst + 2048) = __builtin_convertvector(a2, f32x4);
  *(f32x4*)(dst + 3072) = __builtin_convertvector(a3, f32x4);
}

// ---- reduce 128 f32 partials (f64 chains) + fused epilogue ----
__device__ __forceinline__ void ensemble_epilogue(
    int j, float lateral,
    const float* __restrict__ x, const float* __restrict__ act,
    const float* __restrict__ thr, const float* __restrict__ freq,
    float* __restrict__ out) {
  float na = 0.9f * act[j] + x[j] + lateral;
  float t = thr[j];
  bool sp = na > t;
  float nf = 0.95f * freq[j] + 0.05f * (sp ? 1.0f : 0.0f);
  float nt = (nf > 0.2f) ? (t + 0.05f) : ((nf < 0.2f) ? (t / 1.05f) : t);
  if (sp) na = 0.0f;
  out[j]         = sp ? 1.0f : 0.0f;
  out[S + j]     = na;
  out[2 * S + j] = nt;
  out[3 * S + j] = nf;
}

__global__ __launch_bounds__(TPB) void ensemble_update(
    const float* __restrict__ partial,
    const float* __restrict__ x, const float* __restrict__ act,
    const float* __restrict__ thr, const float* __restrict__ freq,
    float* __restrict__ out) {
  const int j = blockIdx.x * TPB + threadIdx.x;
  double l0 = 0.0, l1 = 0.0, l2 = 0.0, l3 = 0.0;
#pragma unroll 8
  for (int c = 0; c < N_CHUNKS; c += 4) {
    l0 += (double)partial[(size_t)c * S + j];
    l1 += (double)partial[(size_t)(c + 1) * S + j];
    l2 += (double)partial[(size_t)(c + 2) * S + j];
    l3 += (double)partial[(size_t)(c + 3) * S + j];
  }
  ensemble_epilogue(j, (float)((l0 + l1) + (l2 + l3)), x, act, thr, freq, out);
}

// ---- minimal fallback (ws too small; assumes int32 spikes) ----
__global__ __launch_bounds__(TPB) void fused_full_int(
    const float* __restrict__ W, const int* __restrict__ spikes,
    const float* __restrict__ x, const float* __restrict__ act,
    const float* __restrict__ thr, const float* __restrict__ freq,
    float* __restrict__ out) {
  const int j = blockIdx.x * TPB + threadIdx.x;
  double lat = 0.0;
  for (int i = 0; i < S; ++i)
    if (spikes[i] != 0) lat += (double)W[(size_t)i * S + j];
  ensemble_epilogue(j, (float)lat, x, act, thr, freq, out);
}

extern "C" void kernel_launch(void* const* d_in, const int* in_sizes, int n_in,
                              void* d_out, int out_size, void* d_ws, size_t ws_size,
                              hipStream_t stream) {
  const float* x    = (const float*)d_in[0];
  const float* act  = (const float*)d_in[1];
  const float* thr  = (const float*)d_in[2];
  const float* freq = (const float*)d_in[3];
  const float* W    = (const float*)d_in[4];
  const void*  sp   = d_in[5];
  float* out = (float*)d_out;

  // ws: partial f32 @0 (N_CHUNKS*S*4 = 8 MB)
  const size_t need = (size_t)N_CHUNKS * S * sizeof(float);

  if (ws_size >= need) {
    float* partial = (float*)d_ws;
    dim3 g1(COL_BLOCKS, N_CHUNKS);
    lateral_selfprep<<<g1, TPB, 0, stream>>>(W, sp, partial);
    ensemble_update<<<S / TPB, TPB, 0, stream>>>(partial, x, act, thr, freq, out);
  } else {
    fused_full_int<<<S / TPB, TPB, 0, stream>>>(W, (const int*)sp, x, act, thr, freq, out);
  }
}